// Round 2
// baseline (471.258 us; speedup 1.0000x reference)
//
#include <hip/hip_runtime.h>
#include <hip/hip_bf16.h>

#define NB 32
#define CD 256
#define HW 3136
#define XP 3200
#define CG 32

typedef __bf16 bf16;
typedef __attribute__((ext_vector_type(8))) __bf16 bf16x8;
typedef __attribute__((ext_vector_type(4))) float f32x4;

__device__ __forceinline__ void gload_lds16(const void* g, void* l) {
  __builtin_amdgcn_global_load_lds((const __attribute__((address_space(1))) void*)g,
                                   (__attribute__((address_space(3))) void*)l,
                                   16, 0, 0);
}

// ---------------- prep: x [C][HW] f32 -> xT [XP][C] bf16 (pad rows zero) ----------------
__global__ __launch_bounds__(256) void k_prep(const float* __restrict__ x,
                                              bf16* __restrict__ xT) {
  const int b = blockIdx.z, pxt = blockIdx.x, cht = blockIdx.y;
  const int t = threadIdx.x;
  const int px0 = pxt * 64, c0 = cht * 64;
  bf16* xTb = xT + (size_t)b * XP * CD;
  if (pxt == 49) {  // pad region px 3136..3199 -> zeros
    const int j = t >> 2, q = t & 3;
    uint4 z = make_uint4(0u, 0u, 0u, 0u);
    uint4* dst = (uint4*)(xTb + (size_t)(px0 + j) * CD + c0 + q * 16);
    dst[0] = z; dst[1] = z;
    return;
  }
  __shared__ float tile[64][65];
  const float* xb = x + (size_t)b * CD * HW;
  const int i0 = t >> 4, j4 = (t & 15) * 4;
#pragma unroll
  for (int it = 0; it < 4; ++it) {
    int i = it * 16 + i0;
    float4 v = *(const float4*)(xb + (size_t)(c0 + i) * HW + px0 + j4);
    tile[i][j4] = v.x; tile[i][j4 + 1] = v.y; tile[i][j4 + 2] = v.z; tile[i][j4 + 3] = v.w;
  }
  __syncthreads();
  const int j = t >> 2, q = t & 3;
  bf16x8 o2[2];
#pragma unroll
  for (int k = 0; k < 16; ++k) ((bf16*)o2)[k] = (bf16)tile[q * 16 + k][j];
  bf16x8* dst = (bf16x8*)(xTb + (size_t)(px0 + j) * CD + c0 + q * 16);
  dst[0] = o2[0]; dst[1] = o2[1];
}

// ---------------- wcvt: Wp3 f32 -> bf16 ----------------
__global__ __launch_bounds__(256) void k_wcvt(const float* __restrict__ w,
                                              bf16* __restrict__ wb) {
  int i = (blockIdx.x * 256 + threadIdx.x) * 4;
  float4 v = *(const float4*)(w + i);
  bf16 o[4] = {(bf16)v.x, (bf16)v.y, (bf16)v.z, (bf16)v.w};
  *(uint2*)(wb + i) = *(uint2*)o;
}

// ---------------- gconv: grouped 1x1 convs -> lhs, rhs [CD][XP] bf16 ----------------
__global__ __launch_bounds__(256) void k_gconv(const bf16* __restrict__ xT,
                                               const float* __restrict__ Wg1,
                                               const float* __restrict__ bg1,
                                               const float* __restrict__ Wg2,
                                               const float* __restrict__ bg2,
                                               bf16* __restrict__ lhs,
                                               bf16* __restrict__ rhs) {
  const int b = blockIdx.z, gp = blockIdx.y, pxt = blockIdx.x;
  const int t = threadIdx.x, w = t >> 6, l = t & 63;
  const int g = gp * 2 + (w >> 1);
  const int px0 = pxt * 128 + (w & 1) * 64;
  const int lrow = l & 15, lk = l >> 4;
  const bf16* xTb = xT + (size_t)b * XP * CD;
  bf16* lhsb = lhs + (size_t)b * CD * XP;
  bf16* rhsb = rhs + (size_t)b * CD * XP;

  // weight A-fragments (held in regs for whole block)
  bf16x8 a1[2], a2[2];
  const float* w1g = Wg1 + g * CG * CG;
  const float* w2g = Wg2 + g * CG * CG;
#pragma unroll
  for (int m = 0; m < 2; ++m) {
    const float* p1 = w1g + (m * 16 + lrow) * CG + lk * 8;
    const float* p2 = w2g + (m * 16 + lrow) * CG + lk * 8;
#pragma unroll
    for (int jj = 0; jj < 8; ++jj) { a1[m][jj] = (bf16)p1[jj]; a2[m][jj] = (bf16)p2[jj]; }
  }
  const f32x4 z4 = {0.f, 0.f, 0.f, 0.f};
#pragma unroll
  for (int j = 0; j < 4; ++j) {
    const int px = px0 + j * 16;
    const int pxo = px + lrow;  // output column (D col = l&15)
    bf16x8 bv = *(const bf16x8*)(xTb + (size_t)pxo * CD + g * CG + lk * 8);
    f32x4 accL[2] = {z4, z4}, accR[2] = {z4, z4};
#pragma unroll
    for (int m = 0; m < 2; ++m) {
      accL[m] = __builtin_amdgcn_mfma_f32_16x16x32_bf16(a1[m], bv, accL[m], 0, 0, 0);
      accR[m] = __builtin_amdgcn_mfma_f32_16x16x32_bf16(a2[m], bv, accR[m], 0, 0, 0);
    }
    const bool valid = (pxo < HW);  // 3136 is a multiple of 16 -> uniform per lane-group
#pragma unroll
    for (int m = 0; m < 2; ++m)
#pragma unroll
      for (int r = 0; r < 4; ++r) {
        int c = g * CG + m * 16 + lk * 4 + r;
        float vL = valid ? (accL[m][r] + bg1[c]) : 0.f;
        float vR = valid ? (accR[m][r] + bg2[c]) : 0.f;
        lhsb[(size_t)c * XP + pxo] = (bf16)vL;
        rhsb[(size_t)c * XP + pxo] = (bf16)vR;
      }
  }
}

// ---------------- gemm1: t6T[x][o] = max(xT@Wp3^T + bp3, sin(pi/2 * x)) ----------------
__global__ __launch_bounds__(256) void k_gemm1(const bf16* __restrict__ xT,
                                               const bf16* __restrict__ Wp3b,
                                               const float* __restrict__ bp3,
                                               const float* __restrict__ x,
                                               bf16* __restrict__ t6T) {
  __shared__ __attribute__((aligned(16))) bf16 smA[128 * 64];
  __shared__ __attribute__((aligned(16))) bf16 smB[128 * 64];
  const int b = blockIdx.z, mt = blockIdx.x, nt = blockIdx.y;
  const int t = threadIdx.x, w = t >> 6, l = t & 63;
  const int wr = w >> 1, wc = w & 1, lrow = l & 15, lk = l >> 4;
  const bf16* Ab = xT + (size_t)b * XP * CD + (size_t)(mt * 128) * CD;
  const bf16* Bb = Wp3b + (size_t)(nt * 128) * CD;
  const f32x4 z4 = {0.f, 0.f, 0.f, 0.f};
  f32x4 acc[4][4];
#pragma unroll
  for (int m = 0; m < 4; ++m)
#pragma unroll
    for (int n = 0; n < 4; ++n) acc[m][n] = z4;

  for (int kt = 0; kt < CD; kt += 64) {
#pragma unroll
    for (int rr = 0; rr < 4; ++rr) {
      int chunk = rr * 256 + t;
      int row = chunk >> 3;
      int cb = (chunk & 7) * 16;
      int kb = cb ^ ((row & 7) << 4);  // pre-swizzled source (both-sides rule)
      gload_lds16(Ab + (size_t)row * CD + kt + (kb >> 1), (char*)smA + chunk * 16);
      gload_lds16(Bb + (size_t)row * CD + kt + (kb >> 1), (char*)smB + chunk * 16);
    }
    __syncthreads();
#pragma unroll
    for (int kk = 0; kk < 64; kk += 32) {
      bf16x8 af[4], bf[4];
#pragma unroll
      for (int m = 0; m < 4; ++m) {
        int row = wr * 64 + m * 16 + lrow;
        int cb = (kk * 2 + lk * 16) ^ ((row & 7) << 4);
        af[m] = *(const bf16x8*)((const char*)smA + row * 128 + cb);
      }
#pragma unroll
      for (int n = 0; n < 4; ++n) {
        int row = wc * 64 + n * 16 + lrow;
        int cb = (kk * 2 + lk * 16) ^ ((row & 7) << 4);
        bf[n] = *(const bf16x8*)((const char*)smB + row * 128 + cb);
      }
#pragma unroll
      for (int m = 0; m < 4; ++m)
#pragma unroll
        for (int n = 0; n < 4; ++n)
          acc[m][n] = __builtin_amdgcn_mfma_f32_16x16x32_bf16(af[m], bf[n], acc[m][n], 0, 0, 0);
    }
    __syncthreads();
  }
  const int x0 = mt * 128 + wr * 64;
  const int o0 = nt * 128 + wc * 64;
  const float* xb = x + (size_t)b * CD * HW;
  bf16* outb = t6T + (size_t)b * XP * CD;
#pragma unroll
  for (int m = 0; m < 4; ++m)
#pragma unroll
    for (int n = 0; n < 4; ++n) {
      int o = o0 + n * 16 + lrow;
      float bias = bp3[o];
#pragma unroll
      for (int r = 0; r < 4; ++r) {
        int xi = x0 + m * 16 + lk * 4 + r;
        float t3 = acc[m][n][r] + bias;
        float s = 0.f;
        if (xi < HW) s = __sinf(xb[(size_t)o * HW + xi] * 1.57079632679489662f);
        outb[(size_t)xi * CD + o] = (bf16)fmaxf(t3, s);
      }
    }
}

// ---------------- gemm2: t7T[d][c] = (rhs@lhs^T)/56 * p7w[c][d] / 16 ----------------
__global__ __launch_bounds__(256) void k_gemm2(const bf16* __restrict__ lhs,
                                               const bf16* __restrict__ rhs,
                                               const float* __restrict__ p7w,
                                               bf16* __restrict__ t7T) {
  __shared__ __attribute__((aligned(16))) bf16 smA[64 * 64];
  __shared__ __attribute__((aligned(16))) bf16 smB[64 * 64];
  const int b = blockIdx.z, mt = blockIdx.x, nt = blockIdx.y;
  const int t = threadIdx.x, w = t >> 6, l = t & 63;
  const int wr = w >> 1, wc = w & 1, lrow = l & 15, lk = l >> 4;
  const bf16* Ab = rhs + (size_t)b * CD * XP + (size_t)(mt * 64) * XP;
  const bf16* Bb = lhs + (size_t)b * CD * XP + (size_t)(nt * 64) * XP;
  const f32x4 z4 = {0.f, 0.f, 0.f, 0.f};
  f32x4 acc[2][2] = {{z4, z4}, {z4, z4}};
  for (int kt = 0; kt < XP; kt += 64) {
#pragma unroll
    for (int rr = 0; rr < 2; ++rr) {
      int chunk = rr * 256 + t;
      int row = chunk >> 3;
      int cb = (chunk & 7) * 16;
      int kb = cb ^ ((row & 7) << 4);
      gload_lds16(Ab + (size_t)row * XP + kt + (kb >> 1), (char*)smA + chunk * 16);
      gload_lds16(Bb + (size_t)row * XP + kt + (kb >> 1), (char*)smB + chunk * 16);
    }
    __syncthreads();
#pragma unroll
    for (int kk = 0; kk < 64; kk += 32) {
      bf16x8 af[2], bf[2];
#pragma unroll
      for (int m = 0; m < 2; ++m) {
        int row = wr * 32 + m * 16 + lrow;
        int cb = (kk * 2 + lk * 16) ^ ((row & 7) << 4);
        af[m] = *(const bf16x8*)((const char*)smA + row * 128 + cb);
      }
#pragma unroll
      for (int n = 0; n < 2; ++n) {
        int row = wc * 32 + n * 16 + lrow;
        int cb = (kk * 2 + lk * 16) ^ ((row & 7) << 4);
        bf[n] = *(const bf16x8*)((const char*)smB + row * 128 + cb);
      }
#pragma unroll
      for (int m = 0; m < 2; ++m)
#pragma unroll
        for (int n = 0; n < 2; ++n)
          acc[m][n] = __builtin_amdgcn_mfma_f32_16x16x32_bf16(af[m], bf[n], acc[m][n], 0, 0, 0);
    }
    __syncthreads();
  }
  const int d0 = mt * 64 + wr * 32, c0 = nt * 64 + wc * 32;
  bf16* outb = t7T + (size_t)b * CD * CD;
#pragma unroll
  for (int m = 0; m < 2; ++m)
#pragma unroll
    for (int n = 0; n < 2; ++n) {
      int c = c0 + n * 16 + lrow;
#pragma unroll
      for (int r = 0; r < 4; ++r) {
        int d = d0 + m * 16 + lk * 4 + r;
        float v = acc[m][n][r] * (p7w[c * CD + d] * (1.f / 896.f));  // 1/(56*16)
        outb[(size_t)d * CD + c] = (bf16)v;
      }
    }
}

// ---------------- gemm3: out[d][x] = sum_c t7T[d][c] * t6T[x][c] ----------------
__global__ __launch_bounds__(256) void k_gemm3(const bf16* __restrict__ t7T,
                                               const bf16* __restrict__ t6T,
                                               float* __restrict__ out) {
  __shared__ __attribute__((aligned(16))) bf16 smA[128 * 64];
  __shared__ __attribute__((aligned(16))) bf16 smB[128 * 64];
  const int b = blockIdx.z, nt = blockIdx.x, mt = blockIdx.y;
  const int t = threadIdx.x, w = t >> 6, l = t & 63;
  const int wr = w >> 1, wc = w & 1, lrow = l & 15, lk = l >> 4;
  const bf16* Ab = t7T + (size_t)b * CD * CD + (size_t)(mt * 128) * CD;
  const bf16* Bb = t6T + (size_t)b * XP * CD + (size_t)(nt * 128) * CD;
  const f32x4 z4 = {0.f, 0.f, 0.f, 0.f};
  f32x4 acc[4][4];
#pragma unroll
  for (int m = 0; m < 4; ++m)
#pragma unroll
    for (int n = 0; n < 4; ++n) acc[m][n] = z4;
  for (int kt = 0; kt < CD; kt += 64) {
#pragma unroll
    for (int rr = 0; rr < 4; ++rr) {
      int chunk = rr * 256 + t;
      int row = chunk >> 3;
      int cb = (chunk & 7) * 16;
      int kb = cb ^ ((row & 7) << 4);
      gload_lds16(Ab + (size_t)row * CD + kt + (kb >> 1), (char*)smA + chunk * 16);
      gload_lds16(Bb + (size_t)row * CD + kt + (kb >> 1), (char*)smB + chunk * 16);
    }
    __syncthreads();
#pragma unroll
    for (int kk = 0; kk < 64; kk += 32) {
      bf16x8 af[4], bf[4];
#pragma unroll
      for (int m = 0; m < 4; ++m) {
        int row = wr * 64 + m * 16 + lrow;
        int cb = (kk * 2 + lk * 16) ^ ((row & 7) << 4);
        af[m] = *(const bf16x8*)((const char*)smA + row * 128 + cb);
      }
#pragma unroll
      for (int n = 0; n < 4; ++n) {
        int row = wc * 64 + n * 16 + lrow;
        int cb = (kk * 2 + lk * 16) ^ ((row & 7) << 4);
        bf[n] = *(const bf16x8*)((const char*)smB + row * 128 + cb);
      }
#pragma unroll
      for (int m = 0; m < 4; ++m)
#pragma unroll
        for (int n = 0; n < 4; ++n)
          acc[m][n] = __builtin_amdgcn_mfma_f32_16x16x32_bf16(af[m], bf[n], acc[m][n], 0, 0, 0);
    }
    __syncthreads();
  }
  const int d0 = mt * 128 + wr * 64;
  const int xn0 = nt * 128 + wc * 64;
  float* ob = out + (size_t)b * CD * HW;
#pragma unroll
  for (int m = 0; m < 4; ++m)
#pragma unroll
    for (int n = 0; n < 4; ++n) {
      int xcol = xn0 + n * 16 + lrow;
      if (xcol < HW) {  // uniform per 16-lane group (3136 % 16 == 0)
#pragma unroll
        for (int r = 0; r < 4; ++r) {
          int d = d0 + m * 16 + lk * 4 + r;
          ob[(size_t)d * HW + xcol] = acc[m][n][r];
        }
      }
    }
}

extern "C" void kernel_launch(void* const* d_in, const int* in_sizes, int n_in,
                              void* d_out, int out_size, void* d_ws, size_t ws_size,
                              hipStream_t stream) {
  const float* x   = (const float*)d_in[0];
  const float* Wp3 = (const float*)d_in[1];
  const float* bp3 = (const float*)d_in[2];
  const float* Wg1 = (const float*)d_in[3];
  const float* bg1 = (const float*)d_in[4];
  const float* Wg2 = (const float*)d_in[5];
  const float* bg2 = (const float*)d_in[6];
  const float* p7w = (const float*)d_in[7];
  float* out = (float*)d_out;

  char* ws = (char*)d_ws;
  // ws layout (bytes): xT 52428800 | t6T 52428800 | lhs 52428800 | rhs 52428800 | t7T 4194304 | Wp3b 131072
  bf16* xT   = (bf16*)(ws);
  bf16* t6T  = (bf16*)(ws + 52428800);
  bf16* lhs  = (bf16*)(ws + 104857600);
  bf16* rhs  = (bf16*)(ws + 157286400);
  bf16* t7T  = (bf16*)(ws + 209715200);
  bf16* Wp3b = (bf16*)(ws + 213909504);

  k_wcvt<<<dim3(64), 256, 0, stream>>>(Wp3, Wp3b);
  k_prep<<<dim3(50, 4, NB), 256, 0, stream>>>(x, xT);
  k_gconv<<<dim3(25, 4, NB), 256, 0, stream>>>(xT, Wg1, bg1, Wg2, bg2, lhs, rhs);
  k_gemm1<<<dim3(25, 2, NB), 256, 0, stream>>>(xT, Wp3b, bp3, x, t6T);
  k_gemm2<<<dim3(4, 4, NB), 256, 0, stream>>>(lhs, rhs, p7w, t7T);
  k_gemm3<<<dim3(25, 2, NB), 256, 0, stream>>>(t7T, t6T, out);
}

// Round 3
// 335.511 us; speedup vs baseline: 1.4046x; 1.4046x over previous
//
#include <hip/hip_runtime.h>
#include <hip/hip_bf16.h>

#define NB 32
#define CD 256
#define HW 3136
#define XP 3200
#define NQ 4

typedef __bf16 bf16;
typedef __attribute__((ext_vector_type(8))) __bf16 bf16x8;
typedef __attribute__((ext_vector_type(4))) float f32x4;

__device__ __forceinline__ void gload_lds16(const void* g, void* l) {
  __builtin_amdgcn_global_load_lds((const __attribute__((address_space(1))) void*)g,
                                   (__attribute__((address_space(3))) void*)l,
                                   16, 0, 0);
}

// ---- prep: x [C][HW] f32 -> xT [XP][CD] bf16, sinT [XP][CD] bf16, xbf [C][HW] bf16, rsum ----
__global__ __launch_bounds__(256) void k_prep(const float* __restrict__ x,
                                              bf16* __restrict__ xT,
                                              bf16* __restrict__ sT,
                                              bf16* __restrict__ xbf,
                                              float* __restrict__ rsum) {
  const int b = blockIdx.z, pxt = blockIdx.x, cht = blockIdx.y;
  const int t = threadIdx.x;
  const int px0 = pxt * 64, c0 = cht * 64;
  bf16* xTb = xT + (size_t)b * XP * CD;
  bf16* sTb = sT + (size_t)b * XP * CD;
  if (pxt == 49) {  // pad rows 3136..3199 -> zeros in xT and sT
    const int j = t >> 2, q = t & 3;
    uint4 z = {};
    uint4* d1 = (uint4*)(xTb + (size_t)(px0 + j) * CD + c0 + q * 16);
    uint4* d2 = (uint4*)(sTb + (size_t)(px0 + j) * CD + c0 + q * 16);
    d1[0] = z; d1[1] = z; d2[0] = z; d2[1] = z;
    return;
  }
  __shared__ float tile[64][65];
  const float* xb = x + (size_t)b * CD * HW;
  bf16* xbfb = xbf + (size_t)b * CD * HW;
  const int i0 = t >> 4, j4 = (t & 15) * 4;
#pragma unroll
  for (int it = 0; it < 4; ++it) {
    int i = it * 16 + i0;
    float4 v = *(const float4*)(xb + (size_t)(c0 + i) * HW + px0 + j4);
    tile[i][j4] = v.x; tile[i][j4 + 1] = v.y; tile[i][j4 + 2] = v.z; tile[i][j4 + 3] = v.w;
    bf16 o4[4] = {(bf16)v.x, (bf16)v.y, (bf16)v.z, (bf16)v.w};
    *(uint2*)(xbfb + (size_t)(c0 + i) * HW + px0 + j4) = *(uint2*)o4;
  }
  __syncthreads();
  // partial row sums (64 px) -> atomicAdd into rsum[b][c]
  {
    const int i = t >> 2, js = (t & 3) * 16;
    float p = 0.f;
#pragma unroll
    for (int k = 0; k < 16; ++k) p += tile[i][js + k];
    p += __shfl_xor(p, 1);
    p += __shfl_xor(p, 2);
    if ((t & 3) == 0) atomicAdd(rsum + b * CD + c0 + i, p);
  }
  const int j = t >> 2, q = t & 3;
  bf16 xo[16], so[16];
#pragma unroll
  for (int k = 0; k < 16; ++k) {
    float v = tile[q * 16 + k][j];
    xo[k] = (bf16)v;
    so[k] = (bf16)__sinf(v * 1.57079632679489662f);
  }
  bf16x8* d1 = (bf16x8*)(xTb + (size_t)(px0 + j) * CD + c0 + q * 16);
  bf16x8* d2 = (bf16x8*)(sTb + (size_t)(px0 + j) * CD + c0 + q * 16);
  d1[0] = ((bf16x8*)xo)[0]; d1[1] = ((bf16x8*)xo)[1];
  d2[0] = ((bf16x8*)so)[0]; d2[1] = ((bf16x8*)so)[1];
}

// ---- wcvt: Wp3 f32 -> bf16 ----
__global__ __launch_bounds__(256) void k_wcvt(const float* __restrict__ w,
                                              bf16* __restrict__ wb) {
  int i = (blockIdx.x * 256 + threadIdx.x) * 4;
  float4 v = *(const float4*)(w + i);
  bf16 o[4] = {(bf16)v.x, (bf16)v.y, (bf16)v.z, (bf16)v.w};
  *(uint2*)(wb + i) = *(uint2*)o;
}

// ---- gram: Gpart[q][b][c][d] = sum_{x in chunk q} xbf[c][x]*xbf[d][x]  (128^2 tile, split-K=4) ----
__global__ __launch_bounds__(512) void k_gram(const bf16* __restrict__ xbf,
                                              float* __restrict__ Gpart) {
  __shared__ __attribute__((aligned(16))) char sm[32 * 1024];
  bf16* smA = (bf16*)sm;
  bf16* smB = (bf16*)(sm + 16384);
  const int bz = blockIdx.z, b = bz >> 2, q = bz & 3;
  const int mt = blockIdx.x, nt = blockIdx.y;
  const int t = threadIdx.x, w = t >> 6, l = t & 63;
  const int wr = w >> 2, wc = w & 3, lrow = l & 15, lk = l >> 4;
  const bf16* Ab = xbf + (size_t)b * CD * HW + (size_t)(mt * 128) * HW;
  const bf16* Bb = xbf + (size_t)b * CD * HW + (size_t)(nt * 128) * HW;
  const int it0 = q * 13, it1 = (q == 3) ? 49 : (q * 13 + 13);
  const f32x4 z4 = {0.f, 0.f, 0.f, 0.f};
  f32x4 acc[4][2];
#pragma unroll
  for (int m = 0; m < 4; ++m) { acc[m][0] = z4; acc[m][1] = z4; }
  for (int it = it0; it < it1; ++it) {
    const int kt = it * 64;
#pragma unroll
    for (int rr = 0; rr < 2; ++rr) {
      int chunk = rr * 512 + t;
      int row = chunk >> 3, cb = (chunk & 7) * 16;
      int kb = cb ^ ((row & 7) << 4);
      gload_lds16(Ab + (size_t)row * HW + kt + (kb >> 1), sm + chunk * 16);
    }
#pragma unroll
    for (int rr = 0; rr < 2; ++rr) {
      int chunk = rr * 512 + t;
      int row = chunk >> 3, cb = (chunk & 7) * 16;
      int kb = cb ^ ((row & 7) << 4);
      gload_lds16(Bb + (size_t)row * HW + kt + (kb >> 1), sm + 16384 + chunk * 16);
    }
    __syncthreads();
#pragma unroll
    for (int kk = 0; kk < 64; kk += 32) {
      bf16x8 af[4], bfv[2];
#pragma unroll
      for (int m = 0; m < 4; ++m) {
        int row = wr * 64 + m * 16 + lrow;
        int cb = (kk * 2 + lk * 16) ^ ((row & 7) << 4);
        af[m] = *(const bf16x8*)(sm + row * 128 + cb);
      }
#pragma unroll
      for (int n = 0; n < 2; ++n) {
        int row = wc * 32 + n * 16 + lrow;
        int cb = (kk * 2 + lk * 16) ^ ((row & 7) << 4);
        bfv[n] = *(const bf16x8*)(sm + 16384 + row * 128 + cb);
      }
#pragma unroll
      for (int m = 0; m < 4; ++m)
#pragma unroll
        for (int n = 0; n < 2; ++n)
          acc[m][n] = __builtin_amdgcn_mfma_f32_16x16x32_bf16(af[m], bfv[n], acc[m][n], 0, 0, 0);
    }
    __syncthreads();
  }
  float* Gp = Gpart + ((size_t)q * NB + b) * CD * CD + (size_t)(mt * 128) * CD + nt * 128;
#pragma unroll
  for (int m = 0; m < 4; ++m)
#pragma unroll
    for (int n = 0; n < 2; ++n) {
      int col = wc * 32 + n * 16 + lrow;
#pragma unroll
      for (int r = 0; r < 4; ++r) {
        int c = wr * 64 + m * 16 + lk * 4 + r;
        Gp[(size_t)c * CD + col] = acc[m][n][r];
      }
    }
}

// ---- t7chain: t7T[b][d][c] = bf16( (W1.G.W2^T + bias terms)[c][d] * p7w[c][d] / 896 ) ----
__global__ __launch_bounds__(256) void k_t7(const float* __restrict__ Gpart,
                                            const float* __restrict__ Wg1,
                                            const float* __restrict__ bg1,
                                            const float* __restrict__ Wg2,
                                            const float* __restrict__ bg2,
                                            const float* __restrict__ rsum,
                                            const float* __restrict__ p7w,
                                            bf16* __restrict__ t7T) {
  const int gd = blockIdx.x, b = blockIdx.y, t = threadIdx.x;
  __shared__ float Tm[32][256];   // Tm[d'][e]
  __shared__ float W2t[32][32];   // W2t[j][d']
  __shared__ float rb[256];
  __shared__ float u2s[32];
  // per-thread: G row t, columns gd*32..+32 summed over NQ partials; W1 row t
  float gv[32], w1v[32];
#pragma unroll
  for (int j = 0; j < 32; ++j) gv[j] = 0.f;
  for (int q = 0; q < NQ; ++q) {
    const float* Gp = Gpart + ((size_t)q * NB + b) * CD * CD + (size_t)t * CD + gd * 32;
#pragma unroll
    for (int j = 0; j < 32; ++j) gv[j] += Gp[j];
  }
  {
    const float* w1p = Wg1 + t * 32;
#pragma unroll
    for (int i = 0; i < 32; ++i) w1v[i] = w1p[i];
  }
  rb[t] = rsum[b * CD + t];
  if (t < 32) {
    const float* w2p = Wg2 + gd * 1024 + t * 32;
#pragma unroll
    for (int j = 0; j < 32; ++j) W2t[j][t] = w2p[j];
  }
  __syncthreads();
  if (t < 32) {
    float u = 0.f;
#pragma unroll
    for (int j = 0; j < 32; ++j) u += W2t[j][t] * rb[gd * 32 + j];
    u2s[t] = u;
  }
#pragma unroll
  for (int dp = 0; dp < 32; ++dp) {
    float s = 0.f;
#pragma unroll
    for (int j = 0; j < 32; ++j) s += gv[j] * W2t[j][dp];
    Tm[dp][t] = s;
  }
  __syncthreads();
  const int gc = t >> 5;
  float u1c = 0.f;
#pragma unroll
  for (int i = 0; i < 32; ++i) u1c += w1v[i] * rb[gc * 32 + i];
  const float b1c = bg1[t];
  bf16* outb = t7T + (size_t)b * CD * CD;
  const float* p7p = p7w + (size_t)t * CD + gd * 32;
#pragma unroll
  for (int dp = 0; dp < 32; ++dp) {
    float mv = 0.f;
#pragma unroll
    for (int i = 0; i < 32; ++i) mv += w1v[i] * Tm[dp][gc * 32 + i];
    int d = gd * 32 + dp;
    float b2d = bg2[d];
    float tv = mv + u1c * b2d + b1c * u2s[dp] + 3136.f * b1c * b2d;
    float t7v = tv * (p7p[dp] * (1.f / 896.f));  // 1/(56*16)
    outb[(size_t)d * CD + t] = (bf16)t7v;
  }
}

// ---- gemm1: t6T[x][o] = max(xT@Wp3^T + bp3, sinT)   tile 128x x 256o, BK=64 ----
__global__ __launch_bounds__(512) void k_gemm1(const bf16* __restrict__ xT,
                                               const bf16* __restrict__ Wp3b,
                                               const float* __restrict__ bp3,
                                               const bf16* __restrict__ sT,
                                               bf16* __restrict__ t6T) {
  __shared__ __attribute__((aligned(16))) char sm[48 * 1024];  // A 16K | B 32K; epi reuses first 32K
  const int b = blockIdx.z, mt = blockIdx.x;
  const int t = threadIdx.x, w = t >> 6, l = t & 63;
  const int wr = w >> 2, wc = w & 3, lrow = l & 15, lk = l >> 4;
  const bf16* Ab = xT + (size_t)b * XP * CD + (size_t)(mt * 128) * CD;
  const bf16* Bb = Wp3b;
  const f32x4 z4 = {0.f, 0.f, 0.f, 0.f};
  f32x4 acc[4][4];
#pragma unroll
  for (int m = 0; m < 4; ++m)
#pragma unroll
    for (int n = 0; n < 4; ++n) acc[m][n] = z4;
  for (int kt = 0; kt < CD; kt += 64) {
#pragma unroll
    for (int rr = 0; rr < 2; ++rr) {  // A: 128 rows * 8 chunks
      int chunk = rr * 512 + t;
      int row = chunk >> 3, cb = (chunk & 7) * 16;
      int kb = cb ^ ((row & 7) << 4);
      gload_lds16(Ab + (size_t)row * CD + kt + (kb >> 1), sm + chunk * 16);
    }
#pragma unroll
    for (int rr = 0; rr < 4; ++rr) {  // B: 256 rows * 8 chunks
      int chunk = rr * 512 + t;
      int row = chunk >> 3, cb = (chunk & 7) * 16;
      int kb = cb ^ ((row & 7) << 4);
      gload_lds16(Bb + (size_t)row * CD + kt + (kb >> 1), sm + 16384 + chunk * 16);
    }
    __syncthreads();
#pragma unroll
    for (int kk = 0; kk < 64; kk += 32) {
      bf16x8 af[4], bfv[4];
#pragma unroll
      for (int m = 0; m < 4; ++m) {
        int row = wr * 64 + m * 16 + lrow;
        int cb = (kk * 2 + lk * 16) ^ ((row & 7) << 4);
        af[m] = *(const bf16x8*)(sm + row * 128 + cb);
      }
#pragma unroll
      for (int n = 0; n < 4; ++n) {
        int row = wc * 64 + n * 16 + lrow;
        int cb = (kk * 2 + lk * 16) ^ ((row & 7) << 4);
        bfv[n] = *(const bf16x8*)(sm + 16384 + row * 128 + cb);
      }
#pragma unroll
      for (int m = 0; m < 4; ++m)
#pragma unroll
        for (int n = 0; n < 4; ++n)
          acc[m][n] = __builtin_amdgcn_mfma_f32_16x16x32_bf16(af[m], bfv[n], acc[m][n], 0, 0, 0);
    }
    __syncthreads();
  }
  // epilogue: two o-halves through a 128x128 bf16 LDS tile (swizzled), coalesced 16B stores
  bf16* outb = t6T + (size_t)b * XP * CD;
  const bf16* sTb = sT + (size_t)b * XP * CD;
#pragma unroll
  for (int h = 0; h < 2; ++h) {
    __syncthreads();
    if ((wc >> 1) == h) {
#pragma unroll
      for (int m = 0; m < 4; ++m)
#pragma unroll
        for (int n = 0; n < 4; ++n) {
          int o = wc * 64 + n * 16 + lrow;       // global o (within this half's range)
          int col = o - h * 128;
          float bias = bp3[o];
#pragma unroll
          for (int r = 0; r < 4; ++r) {
            int row = wr * 64 + m * 16 + lk * 4 + r;
            int ba = row * 256 + ((col * 2) ^ (((row >> 2) & 3) << 4));
            *(bf16*)(sm + ba) = (bf16)(acc[m][n][r] + bias);
          }
        }
    }
    __syncthreads();
#pragma unroll
    for (int it = 0; it < 4; ++it) {
      int chunk = it * 512 + t;
      int row = chunk >> 4;
      int cb16 = (chunk & 15) * 16;
      int ba = row * 256 + (cb16 ^ (((row >> 2) & 3) << 4));
      bf16x8 v = *(const bf16x8*)(sm + ba);
      size_t gi = (size_t)(mt * 128 + row) * CD + h * 128 + (chunk & 15) * 8;
      bf16x8 sv = *(const bf16x8*)(sTb + gi);
      bf16x8 ov;
#pragma unroll
      for (int e = 0; e < 8; ++e) {
        float a = (float)v[e], s = (float)sv[e];
        ov[e] = (bf16)fmaxf(a, s);
      }
      *(bf16x8*)(outb + gi) = ov;
    }
  }
}

// ---- gemm3: out[d][x] = sum_c t7T[d][c] * t6T[x][c]   tile 256d x 128x, BK=64 ----
__global__ __launch_bounds__(512) void k_gemm3(const bf16* __restrict__ t7T,
                                               const bf16* __restrict__ t6T,
                                               float* __restrict__ out) {
  __shared__ __attribute__((aligned(16))) char sm[48 * 1024];  // A 32K | B 16K
  const int b = blockIdx.z, xt = blockIdx.x;
  const int t = threadIdx.x, w = t >> 6, l = t & 63;
  const int wr = w >> 1, wc = w & 1, lrow = l & 15, lk = l >> 4;
  const bf16* Ab = t7T + (size_t)b * CD * CD;
  const bf16* Bb = t6T + (size_t)b * XP * CD + (size_t)(xt * 128) * CD;
  const f32x4 z4 = {0.f, 0.f, 0.f, 0.f};
  f32x4 acc[4][4];
#pragma unroll
  for (int m = 0; m < 4; ++m)
#pragma unroll
    for (int n = 0; n < 4; ++n) acc[m][n] = z4;
  for (int kt = 0; kt < CD; kt += 64) {
#pragma unroll
    for (int rr = 0; rr < 4; ++rr) {  // A: 256 rows * 8 chunks
      int chunk = rr * 512 + t;
      int row = chunk >> 3, cb = (chunk & 7) * 16;
      int kb = cb ^ ((row & 7) << 4);
      gload_lds16(Ab + (size_t)row * CD + kt + (kb >> 1), sm + chunk * 16);
    }
#pragma unroll
    for (int rr = 0; rr < 2; ++rr) {  // B: 128 rows * 8 chunks
      int chunk = rr * 512 + t;
      int row = chunk >> 3, cb = (chunk & 7) * 16;
      int kb = cb ^ ((row & 7) << 4);
      gload_lds16(Bb + (size_t)row * CD + kt + (kb >> 1), sm + 32768 + chunk * 16);
    }
    __syncthreads();
#pragma unroll
    for (int kk = 0; kk < 64; kk += 32) {
      bf16x8 af[4], bfv[4];
#pragma unroll
      for (int m = 0; m < 4; ++m) {
        int row = wr * 64 + m * 16 + lrow;
        int cb = (kk * 2 + lk * 16) ^ ((row & 7) << 4);
        af[m] = *(const bf16x8*)(sm + row * 128 + cb);
      }
#pragma unroll
      for (int n = 0; n < 4; ++n) {
        int row = wc * 64 + n * 16 + lrow;
        int cb = (kk * 2 + lk * 16) ^ ((row & 7) << 4);
        bfv[n] = *(const bf16x8*)(sm + 32768 + row * 128 + cb);
      }
#pragma unroll
      for (int m = 0; m < 4; ++m)
#pragma unroll
        for (int n = 0; n < 4; ++n)
          acc[m][n] = __builtin_amdgcn_mfma_f32_16x16x32_bf16(af[m], bfv[n], acc[m][n], 0, 0, 0);
    }
    __syncthreads();
  }
  float* ob = out + (size_t)b * CD * HW;
#pragma unroll
  for (int m = 0; m < 4; ++m)
#pragma unroll
    for (int n = 0; n < 4; ++n) {
      int xcol = xt * 128 + wc * 64 + n * 16 + lrow;
      if (xcol < HW) {  // uniform per 16-lane group (3136 % 16 == 0)
#pragma unroll
        for (int r = 0; r < 4; ++r) {
          int d = wr * 64 + m * 16 + lk * 4 + r;
          ob[(size_t)d * HW + xcol] = acc[m][n][r];
        }
      }
    }
}

extern "C" void kernel_launch(void* const* d_in, const int* in_sizes, int n_in,
                              void* d_out, int out_size, void* d_ws, size_t ws_size,
                              hipStream_t stream) {
  const float* x   = (const float*)d_in[0];
  const float* Wp3 = (const float*)d_in[1];
  const float* bp3 = (const float*)d_in[2];
  const float* Wg1 = (const float*)d_in[3];
  const float* bg1 = (const float*)d_in[4];
  const float* Wg2 = (const float*)d_in[5];
  const float* bg2 = (const float*)d_in[6];
  const float* p7w = (const float*)d_in[7];
  float* out = (float*)d_out;

  char* ws = (char*)d_ws;
  // layout (bytes):
  // xT    @ 0          (52,428,800)
  // sT    @ 52428800   (52,428,800)
  // xbf   @ 104857600  (51,380,224)   [dead after gram]
  // Gpart @ 156237824  (33,554,432)   [dead after t7]
  // t7T   @ 189792256  ( 4,194,304)
  // Wp3b  @ 193986560  (   131,072)
  // rsum  @ 194117632  (    32,768)
  // t6T aliases xbf + first 1MB of Gpart (written by gemm1 AFTER both are dead)
  bf16*  xT    = (bf16*)(ws);
  bf16*  sT    = (bf16*)(ws + 52428800);
  bf16*  xbf   = (bf16*)(ws + 104857600);
  float* Gpart = (float*)(ws + 156237824);
  bf16*  t7T   = (bf16*)(ws + 189792256);
  bf16*  Wp3b  = (bf16*)(ws + 193986560);
  float* rsum  = (float*)(ws + 194117632);
  bf16*  t6T   = (bf16*)(ws + 104857600);  // alias, see above

  hipMemsetAsync(rsum, 0, NB * CD * sizeof(float), stream);
  k_wcvt<<<dim3(64), 256, 0, stream>>>(Wp3, Wp3b);
  k_prep<<<dim3(50, 4, NB), 256, 0, stream>>>(x, xT, sT, xbf, rsum);
  k_gram<<<dim3(2, 2, NB * NQ), 512, 0, stream>>>(xbf, Gpart);
  k_t7<<<dim3(8, NB), 256, 0, stream>>>(Gpart, Wg1, bg1, Wg2, bg2, rsum, p7w, t7T);
  k_gemm1<<<dim3(25, 1, NB), 512, 0, stream>>>(xT, Wp3b, bp3, sT, t6T);
  k_gemm3<<<dim3(25, 1, NB), 512, 0, stream>>>(t7T, t6T, out);
}

// Round 4
// 310.643 us; speedup vs baseline: 1.5170x; 1.0801x over previous
//
#include <hip/hip_runtime.h>
#include <hip/hip_bf16.h>

#define NB 32
#define CD 256
#define HW 3136
#define XP 3200
#define NQ 4

typedef __bf16 bf16;
typedef __attribute__((ext_vector_type(8))) __bf16 bf16x8;
typedef __attribute__((ext_vector_type(4))) float f32x4;

__device__ __forceinline__ void gload_lds16(const void* g, void* l) {
  __builtin_amdgcn_global_load_lds((const __attribute__((address_space(1))) void*)g,
                                   (__attribute__((address_space(3))) void*)l,
                                   16, 0, 0);
}

// ---- prep: x [C][HW] f32 -> xT [XP][CD] bf16 (pad rows zero) + rsum[b][c] ----
__global__ __launch_bounds__(256) void k_prep(const float* __restrict__ x,
                                              bf16* __restrict__ xT,
                                              float* __restrict__ rsum) {
  const int b = blockIdx.z, pxt = blockIdx.x, cht = blockIdx.y;
  const int t = threadIdx.x;
  const int px0 = pxt * 64, c0 = cht * 64;
  bf16* xTb = xT + (size_t)b * XP * CD;
  if (pxt == 49) {  // pad rows 3136..3199 -> zeros
    const int j = t >> 2, q = t & 3;
    uint4 z = {};
    uint4* d1 = (uint4*)(xTb + (size_t)(px0 + j) * CD + c0 + q * 16);
    d1[0] = z; d1[1] = z;
    return;
  }
  __shared__ float tile[64][65];
  const float* xb = x + (size_t)b * CD * HW;
  const int i0 = t >> 4, j4 = (t & 15) * 4;
#pragma unroll
  for (int it = 0; it < 4; ++it) {
    int i = it * 16 + i0;
    float4 v = *(const float4*)(xb + (size_t)(c0 + i) * HW + px0 + j4);
    tile[i][j4] = v.x; tile[i][j4 + 1] = v.y; tile[i][j4 + 2] = v.z; tile[i][j4 + 3] = v.w;
  }
  __syncthreads();
  // partial row sums (64 px) -> atomicAdd into rsum[b][c]
  {
    const int i = t >> 2, js = (t & 3) * 16;
    float p = 0.f;
#pragma unroll
    for (int k = 0; k < 16; ++k) p += tile[i][js + k];
    p += __shfl_xor(p, 1);
    p += __shfl_xor(p, 2);
    if ((t & 3) == 0) atomicAdd(rsum + b * CD + c0 + i, p);
  }
  const int j = t >> 2, q = t & 3;
  bf16 xo[16];
#pragma unroll
  for (int k = 0; k < 16; ++k) xo[k] = (bf16)tile[q * 16 + k][j];
  bf16x8* d1 = (bf16x8*)(xTb + (size_t)(px0 + j) * CD + c0 + q * 16);
  d1[0] = ((bf16x8*)xo)[0]; d1[1] = ((bf16x8*)xo)[1];
}

// ---- wcvt: Wp3 f32 -> bf16 ----
__global__ __launch_bounds__(256) void k_wcvt(const float* __restrict__ w,
                                              bf16* __restrict__ wb) {
  int i = (blockIdx.x * 256 + threadIdx.x) * 4;
  float4 v = *(const float4*)(w + i);
  bf16 o[4] = {(bf16)v.x, (bf16)v.y, (bf16)v.z, (bf16)v.w};
  *(uint2*)(wb + i) = *(uint2*)o;
}

// ---- gram: Gpart[q][b][c][d] = sum_{px in chunk q} x[c][px]*x[d][px]
//      reads f32 x directly; reg-staged cvt to bf16 LDS tile [256c][64px] (swizzled),
//      tile shared by A (mt half rows) and B (all 256 cols). grid (mt2, NQ, NB), 512 thr.
#define GRAM_LOAD(ITV)                                                  \
  {                                                                     \
    const int kt = (ITV) * 64;                                          \
    _Pragma("unroll")                                                   \
    for (int s8 = 0; s8 < 8; ++s8) {                                    \
      int s = s8 * 512 + t;                                             \
      int c = s >> 4, p4 = s & 15;                                      \
      rv[s8] = *(const float4*)(xb + (size_t)c * HW + kt + p4 * 4);     \
    }                                                                   \
  }

__global__ __launch_bounds__(512) void k_gram(const float* __restrict__ x,
                                              float* __restrict__ Gpart) {
  __shared__ __attribute__((aligned(16))) char sm[32 * 1024];
  const int b = blockIdx.z, q = blockIdx.y, mt = blockIdx.x;
  const int t = threadIdx.x, w = t >> 6, l = t & 63;
  const int wr = w >> 2, wc = w & 3, lrow = l & 15, lk = l >> 4;
  const float* xb = x + (size_t)b * CD * HW;
  const int it0 = (q * 49) / NQ, it1 = ((q + 1) * 49) / NQ;
  const f32x4 z4 = {0.f, 0.f, 0.f, 0.f};
  f32x4 acc[4][4];
#pragma unroll
  for (int m = 0; m < 4; ++m)
#pragma unroll
    for (int n = 0; n < 4; ++n) acc[m][n] = z4;

  float4 rv[8];
  GRAM_LOAD(it0);
  for (int it = it0; it < it1; ++it) {
#pragma unroll
    for (int s8 = 0; s8 < 8; ++s8) {
      int s = s8 * 512 + t;
      int c = s >> 4, p4 = s & 15;
      bf16 o4[4] = {(bf16)rv[s8].x, (bf16)rv[s8].y, (bf16)rv[s8].z, (bf16)rv[s8].w};
      int ba = c * 128 + ((p4 * 8) ^ ((c & 7) << 4));
      *(uint2*)(sm + ba) = *(uint2*)o4;
    }
    __syncthreads();
    if (it + 1 < it1) GRAM_LOAD(it + 1);  // issue-early; hides under compute
#pragma unroll
    for (int kk = 0; kk < 64; kk += 32) {
      bf16x8 af[4], bfv[4];
#pragma unroll
      for (int m = 0; m < 4; ++m) {
        int row = mt * 128 + wr * 64 + m * 16 + lrow;
        int ba = row * 128 + ((kk * 2 + lk * 16) ^ ((row & 7) << 4));
        af[m] = *(const bf16x8*)(sm + ba);
      }
#pragma unroll
      for (int n = 0; n < 4; ++n) {
        int row = wc * 64 + n * 16 + lrow;
        int ba = row * 128 + ((kk * 2 + lk * 16) ^ ((row & 7) << 4));
        bfv[n] = *(const bf16x8*)(sm + ba);
      }
#pragma unroll
      for (int m = 0; m < 4; ++m)
#pragma unroll
        for (int n = 0; n < 4; ++n)
          acc[m][n] = __builtin_amdgcn_mfma_f32_16x16x32_bf16(af[m], bfv[n], acc[m][n], 0, 0, 0);
    }
    __syncthreads();
  }
  float* Gp = Gpart + ((size_t)q * NB + b) * CD * CD + (size_t)(mt * 128) * CD;
#pragma unroll
  for (int m = 0; m < 4; ++m)
#pragma unroll
    for (int n = 0; n < 4; ++n) {
      int d = wc * 64 + n * 16 + lrow;
#pragma unroll
      for (int r = 0; r < 4; ++r) {
        int c = wr * 64 + m * 16 + lk * 4 + r;
        Gp[(size_t)c * CD + d] = acc[m][n][r];
      }
    }
}

// ---- t7chain: t7T[b][d][c] = bf16( (W1.G.W2^T + bias terms)[c][d] * p7w[c][d] / 896 ) ----
__global__ __launch_bounds__(256) void k_t7(const float* __restrict__ Gpart,
                                            const float* __restrict__ Wg1,
                                            const float* __restrict__ bg1,
                                            const float* __restrict__ Wg2,
                                            const float* __restrict__ bg2,
                                            const float* __restrict__ rsum,
                                            const float* __restrict__ p7w,
                                            bf16* __restrict__ t7T) {
  const int gd = blockIdx.x, b = blockIdx.y, t = threadIdx.x;
  __shared__ float Tm[32][256];   // Tm[d'][e]
  __shared__ float W2t[32][32];   // W2t[j][d']
  __shared__ float rb[256];
  __shared__ float u2s[32];
  float gv[32], w1v[32];
#pragma unroll
  for (int j = 0; j < 32; ++j) gv[j] = 0.f;
  for (int q = 0; q < NQ; ++q) {
    const float* Gp = Gpart + ((size_t)q * NB + b) * CD * CD + (size_t)t * CD + gd * 32;
#pragma unroll
    for (int j = 0; j < 32; ++j) gv[j] += Gp[j];
  }
  {
    const float* w1p = Wg1 + t * 32;
#pragma unroll
    for (int i = 0; i < 32; ++i) w1v[i] = w1p[i];
  }
  rb[t] = rsum[b * CD + t];
  if (t < 32) {
    const float* w2p = Wg2 + gd * 1024 + t * 32;
#pragma unroll
    for (int j = 0; j < 32; ++j) W2t[j][t] = w2p[j];
  }
  __syncthreads();
  if (t < 32) {
    float u = 0.f;
#pragma unroll
    for (int j = 0; j < 32; ++j) u += W2t[j][t] * rb[gd * 32 + j];
    u2s[t] = u;
  }
#pragma unroll
  for (int dp = 0; dp < 32; ++dp) {
    float s = 0.f;
#pragma unroll
    for (int j = 0; j < 32; ++j) s += gv[j] * W2t[j][dp];
    Tm[dp][t] = s;
  }
  __syncthreads();
  const int gc = t >> 5;
  float u1c = 0.f;
#pragma unroll
  for (int i = 0; i < 32; ++i) u1c += w1v[i] * rb[gc * 32 + i];
  const float b1c = bg1[t];
  bf16* outb = t7T + (size_t)b * CD * CD;
  const float* p7p = p7w + (size_t)t * CD + gd * 32;
#pragma unroll
  for (int dp = 0; dp < 32; ++dp) {
    float mv = 0.f;
#pragma unroll
    for (int i = 0; i < 32; ++i) mv += w1v[i] * Tm[dp][gc * 32 + i];
    int d = gd * 32 + dp;
    float b2d = bg2[d];
    float tv = mv + u1c * b2d + b1c * u2s[dp] + 3136.f * b1c * b2d;
    float t7v = tv * (p7p[dp] * (1.f / 896.f));  // 1/(56*16)
    outb[(size_t)d * CD + t] = (bf16)t7v;
  }
}

// ---- gemm1: t6T[x][o] = max(xT@Wp3^T + bp3, sin(pi/2 * xT))  tile 128x x 256o, BK=64 ----
__global__ __launch_bounds__(512) void k_gemm1(const bf16* __restrict__ xT,
                                               const bf16* __restrict__ Wp3b,
                                               const float* __restrict__ bp3,
                                               bf16* __restrict__ t6T) {
  __shared__ __attribute__((aligned(16))) char sm[48 * 1024];  // A 16K | B 32K; epi reuses first 32K
  const int b = blockIdx.z, mt = blockIdx.x;
  const int t = threadIdx.x, w = t >> 6, l = t & 63;
  const int wr = w >> 2, wc = w & 3, lrow = l & 15, lk = l >> 4;
  const bf16* xTb = xT + (size_t)b * XP * CD;
  const bf16* Ab = xTb + (size_t)(mt * 128) * CD;
  const bf16* Bb = Wp3b;
  const f32x4 z4 = {0.f, 0.f, 0.f, 0.f};
  f32x4 acc[4][4];
#pragma unroll
  for (int m = 0; m < 4; ++m)
#pragma unroll
    for (int n = 0; n < 4; ++n) acc[m][n] = z4;
  for (int kt = 0; kt < CD; kt += 64) {
#pragma unroll
    for (int rr = 0; rr < 2; ++rr) {  // A: 128 rows * 8 chunks
      int chunk = rr * 512 + t;
      int row = chunk >> 3, cb = (chunk & 7) * 16;
      int kb = cb ^ ((row & 7) << 4);
      gload_lds16(Ab + (size_t)row * CD + kt + (kb >> 1), sm + chunk * 16);
    }
#pragma unroll
    for (int rr = 0; rr < 4; ++rr) {  // B: 256 rows * 8 chunks
      int chunk = rr * 512 + t;
      int row = chunk >> 3, cb = (chunk & 7) * 16;
      int kb = cb ^ ((row & 7) << 4);
      gload_lds16(Bb + (size_t)row * CD + kt + (kb >> 1), sm + 16384 + chunk * 16);
    }
    __syncthreads();
#pragma unroll
    for (int kk = 0; kk < 64; kk += 32) {
      bf16x8 af[4], bfv[4];
#pragma unroll
      for (int m = 0; m < 4; ++m) {
        int row = wr * 64 + m * 16 + lrow;
        int cb = (kk * 2 + lk * 16) ^ ((row & 7) << 4);
        af[m] = *(const bf16x8*)(sm + row * 128 + cb);
      }
#pragma unroll
      for (int n = 0; n < 4; ++n) {
        int row = wc * 64 + n * 16 + lrow;
        int cb = (kk * 2 + lk * 16) ^ ((row & 7) << 4);
        bfv[n] = *(const bf16x8*)(sm + 16384 + row * 128 + cb);
      }
#pragma unroll
      for (int m = 0; m < 4; ++m)
#pragma unroll
        for (int n = 0; n < 4; ++n)
          acc[m][n] = __builtin_amdgcn_mfma_f32_16x16x32_bf16(af[m], bfv[n], acc[m][n], 0, 0, 0);
    }
    __syncthreads();
  }
  // epilogue: two o-halves through a 128x128 bf16 LDS tile (swizzled), coalesced 16B stores;
  // sin recomputed from xT (bf16) -- no sT stream.
  bf16* outb = t6T + (size_t)b * XP * CD;
#pragma unroll
  for (int h = 0; h < 2; ++h) {
    __syncthreads();
    if ((wc >> 1) == h) {
#pragma unroll
      for (int m = 0; m < 4; ++m)
#pragma unroll
        for (int n = 0; n < 4; ++n) {
          int o = wc * 64 + n * 16 + lrow;
          int col = o - h * 128;
          float bias = bp3[o];
#pragma unroll
          for (int r = 0; r < 4; ++r) {
            int row = wr * 64 + m * 16 + lk * 4 + r;
            int ba = row * 256 + ((col * 2) ^ (((row >> 2) & 3) << 4));
            *(bf16*)(sm + ba) = (bf16)(acc[m][n][r] + bias);
          }
        }
    }
    __syncthreads();
#pragma unroll
    for (int it = 0; it < 4; ++it) {
      int chunk = it * 512 + t;
      int row = chunk >> 4;
      int cb16 = (chunk & 15) * 16;
      int ba = row * 256 + (cb16 ^ (((row >> 2) & 3) << 4));
      bf16x8 v = *(const bf16x8*)(sm + ba);
      size_t gi = (size_t)(mt * 128 + row) * CD + h * 128 + (chunk & 15) * 8;
      bf16x8 xv = *(const bf16x8*)(xTb + gi);
      bf16x8 ov;
#pragma unroll
      for (int e = 0; e < 8; ++e) {
        float a = (float)v[e];
        float s = __sinf((float)xv[e] * 1.57079632679489662f);
        ov[e] = (bf16)fmaxf(a, s);
      }
      *(bf16x8*)(outb + gi) = ov;
    }
  }
}

// ---- gemm3: out[d][x] = sum_c t7T[d][c] * t6T[x][c]   tile 256d x 128x, BK=64 ----
__global__ __launch_bounds__(512) void k_gemm3(const bf16* __restrict__ t7T,
                                               const bf16* __restrict__ t6T,
                                               float* __restrict__ out) {
  __shared__ __attribute__((aligned(16))) char sm[48 * 1024];  // A 32K | B 16K
  const int b = blockIdx.z, xt = blockIdx.x;
  const int t = threadIdx.x, w = t >> 6, l = t & 63;
  const int wr = w >> 1, wc = w & 1, lrow = l & 15, lk = l >> 4;
  const bf16* Ab = t7T + (size_t)b * CD * CD;
  const bf16* Bb = t6T + (size_t)b * XP * CD + (size_t)(xt * 128) * CD;
  const f32x4 z4 = {0.f, 0.f, 0.f, 0.f};
  f32x4 acc[4][4];
#pragma unroll
  for (int m = 0; m < 4; ++m)
#pragma unroll
    for (int n = 0; n < 4; ++n) acc[m][n] = z4;
  for (int kt = 0; kt < CD; kt += 64) {
#pragma unroll
    for (int rr = 0; rr < 4; ++rr) {  // A: 256 rows * 8 chunks
      int chunk = rr * 512 + t;
      int row = chunk >> 3, cb = (chunk & 7) * 16;
      int kb = cb ^ ((row & 7) << 4);
      gload_lds16(Ab + (size_t)row * CD + kt + (kb >> 1), sm + chunk * 16);
    }
#pragma unroll
    for (int rr = 0; rr < 2; ++rr) {  // B: 128 rows * 8 chunks
      int chunk = rr * 512 + t;
      int row = chunk >> 3, cb = (chunk & 7) * 16;
      int kb = cb ^ ((row & 7) << 4);
      gload_lds16(Bb + (size_t)row * CD + kt + (kb >> 1), sm + 32768 + chunk * 16);
    }
    __syncthreads();
#pragma unroll
    for (int kk = 0; kk < 64; kk += 32) {
      bf16x8 af[4], bfv[4];
#pragma unroll
      for (int m = 0; m < 4; ++m) {
        int row = wr * 64 + m * 16 + lrow;
        int cb = (kk * 2 + lk * 16) ^ ((row & 7) << 4);
        af[m] = *(const bf16x8*)(sm + row * 128 + cb);
      }
#pragma unroll
      for (int n = 0; n < 4; ++n) {
        int row = wc * 64 + n * 16 + lrow;
        int cb = (kk * 2 + lk * 16) ^ ((row & 7) << 4);
        bfv[n] = *(const bf16x8*)(sm + 32768 + row * 128 + cb);
      }
#pragma unroll
      for (int m = 0; m < 4; ++m)
#pragma unroll
        for (int n = 0; n < 4; ++n)
          acc[m][n] = __builtin_amdgcn_mfma_f32_16x16x32_bf16(af[m], bfv[n], acc[m][n], 0, 0, 0);
    }
    __syncthreads();
  }
  float* ob = out + (size_t)b * CD * HW;
#pragma unroll
  for (int m = 0; m < 4; ++m)
#pragma unroll
    for (int n = 0; n < 4; ++n) {
      int xcol = xt * 128 + wc * 64 + n * 16 + lrow;
      if (xcol < HW) {  // uniform per 16-lane group (3136 % 16 == 0)
#pragma unroll
        for (int r = 0; r < 4; ++r) {
          int d = wr * 64 + m * 16 + lk * 4 + r;
          ob[(size_t)d * HW + xcol] = acc[m][n][r];
        }
      }
    }
}

extern "C" void kernel_launch(void* const* d_in, const int* in_sizes, int n_in,
                              void* d_out, int out_size, void* d_ws, size_t ws_size,
                              hipStream_t stream) {
  const float* x   = (const float*)d_in[0];
  const float* Wp3 = (const float*)d_in[1];
  const float* bp3 = (const float*)d_in[2];
  const float* Wg1 = (const float*)d_in[3];
  const float* bg1 = (const float*)d_in[4];
  const float* Wg2 = (const float*)d_in[5];
  const float* bg2 = (const float*)d_in[6];
  const float* p7w = (const float*)d_in[7];
  float* out = (float*)d_out;

  char* ws = (char*)d_ws;
  // layout (bytes):
  // xT    @ 0           (52,428,800)
  // t6T   @ 52,428,800  (52,428,800)
  // Gpart @ 104,857,600 (33,554,432)
  // t7T   @ 138,412,032 ( 4,194,304)
  // Wp3b  @ 142,606,336 (   131,072)
  // rsum  @ 142,737,408 (    32,768)
  bf16*  xT    = (bf16*)(ws);
  bf16*  t6T   = (bf16*)(ws + 52428800);
  float* Gpart = (float*)(ws + 104857600);
  bf16*  t7T   = (bf16*)(ws + 138412032);
  bf16*  Wp3b  = (bf16*)(ws + 142606336);
  float* rsum  = (float*)(ws + 142737408);

  hipMemsetAsync(rsum, 0, NB * CD * sizeof(float), stream);
  k_wcvt<<<dim3(64), 256, 0, stream>>>(Wp3, Wp3b);
  k_prep<<<dim3(50, 4, NB), 256, 0, stream>>>(x, xT, rsum);
  k_gram<<<dim3(2, NQ, NB), 512, 0, stream>>>(x, Gpart);
  k_t7<<<dim3(8, NB), 256, 0, stream>>>(Gpart, Wg1, bg1, Wg2, bg2, rsum, p7w, t7T);
  k_gemm1<<<dim3(25, 1, NB), 512, 0, stream>>>(xT, Wp3b, bp3, t6T);
  k_gemm3<<<dim3(25, 1, NB), 512, 0, stream>>>(t7T, t6T, out);
}